// Round 11
// baseline (549.946 us; speedup 1.0000x reference)
//
#include <hip/hip_runtime.h>
#include <hip/hip_bf16.h>

typedef __hip_bfloat16 bf16;

#define B_     8
#define N_     64
#define H_     512
#define HEADS_ 8
#define SP_    64
#define L_     4
static constexpr float INV_SCALE = 0.044194173824159216f; // 1/sqrt(512)

typedef __attribute__((ext_vector_type(8))) short short8;
typedef __attribute__((ext_vector_type(4))) float f32x4;

__device__ __forceinline__ void gload_lds16(const void* g, void* l) {
    __builtin_amdgcn_global_load_lds(
        (const __attribute__((address_space(1))) unsigned int*)g,
        (__attribute__((address_space(3))) unsigned int*)l, 16, 0, 0);
}

__device__ __forceinline__ void unpack8(uint4 u, float* f) {
    f[0] = __uint_as_float(u.x << 16); f[1] = __uint_as_float(u.x & 0xffff0000u);
    f[2] = __uint_as_float(u.y << 16); f[3] = __uint_as_float(u.y & 0xffff0000u);
    f[4] = __uint_as_float(u.z << 16); f[5] = __uint_as_float(u.z & 0xffff0000u);
    f[6] = __uint_as_float(u.w << 16); f[7] = __uint_as_float(u.w & 0xffff0000u);
}

__device__ __forceinline__ bf16 f2bf(float v) { return __float2bfloat16(v); }

#define BM 128
#define BN 128
#define BK 32
#define RSTR 80

// ------------------------------------------------------------ GEMM bodies
template <int EPI>
__device__ __forceinline__ void gemm128_body(char* lds,
        const bf16* __restrict__ A, const bf16* __restrict__ Bt,
        void* __restrict__ Cv, const float* __restrict__ R,
        int M, int N, int K, int bx, int by) {
    char* As = lds;
    char* Bs = lds + BM * 64;
    const int tid = threadIdx.x;
    const int bm = bx * BM, bn = by * BN;
    const int w = tid >> 6, lane = tid & 63;
    const int wr = (w >> 1) * 64, wc = (w & 1) * 64;
    const int m0 = lane & 15, q4 = lane >> 4;

    f32x4 acc[4][4] = {};

    const int sr = lane >> 2;
    const int scE = (((lane & 3) ^ (sr & 3)) * 8);
    const int fr = m0 * 64 + ((q4 ^ (m0 & 3)) * 16);

    for (int k0 = 0; k0 < K; k0 += BK) {
        __syncthreads();
        #pragma unroll
        for (int t = 0; t < 2; ++t) {
            gload_lds16(A  + (size_t)(bm + w * 32 + t * 16 + sr) * K + k0 + scE,
                        As + (w * 2 + t) * 1024);
            gload_lds16(Bt + (size_t)(bn + w * 32 + t * 16 + sr) * K + k0 + scE,
                        Bs + (w * 2 + t) * 1024);
        }
        __syncthreads();
        short8 af[4], bfr[4];
        #pragma unroll
        for (int t = 0; t < 4; ++t) {
            af[t]  = *(const short8*)(As + (wr / 16 + t) * 1024 + fr);
            bfr[t] = *(const short8*)(Bs + (wc / 16 + t) * 1024 + fr);
        }
        #pragma unroll
        for (int mt = 0; mt < 4; ++mt)
            #pragma unroll
            for (int nt = 0; nt < 4; ++nt)
                acc[mt][nt] = __builtin_amdgcn_mfma_f32_16x16x32_bf16(
                    af[mt], bfr[nt], acc[mt][nt], 0, 0, 0);
    }

    if (EPI <= 1) {
        float* C = (float*)Cv;
        #pragma unroll
        for (int mt = 0; mt < 4; ++mt)
            #pragma unroll
            for (int i = 0; i < 4; ++i) {
                int row = bm + wr + mt * 16 + q4 * 4 + i;
                #pragma unroll
                for (int nt = 0; nt < 4; ++nt) {
                    int col = bn + wc + nt * 16 + m0;
                    float v = acc[mt][nt][i];
                    if (EPI == 1) v += R[(size_t)row * N + col];
                    C[(size_t)row * N + col] = v;
                }
            }
    } else {
        bf16* C = (bf16*)Cv;
        #pragma unroll
        for (int mt = 0; mt < 4; ++mt)
            #pragma unroll
            for (int i = 0; i < 4; ++i) {
                int row = bm + wr + mt * 16 + q4 * 4 + i;
                #pragma unroll
                for (int nt = 0; nt < 4; ++nt) {
                    int col = bn + wc + nt * 16 + m0;
                    float v = acc[mt][nt][i];
                    if (EPI == 2) v = fmaxf(v, 0.0f);
                    C[(size_t)row * N + col] = __float2bfloat16(v);
                }
            }
    }
}

template <int EPI>
__device__ __forceinline__ void gemm64_body(char* lds,
        const bf16* __restrict__ A, const bf16* __restrict__ Bt,
        void* __restrict__ Cv, const float* __restrict__ R,
        int M, int N, int K, int bx, int by, int kbeg, int kend) {
    char* As = lds;
    char* Bs = lds + 2 * 64 * RSTR;
    const int tid = threadIdx.x;
    const int bm = bx * 64, bn = by * 64;
    const int w = tid >> 6, lane = tid & 63;
    const int wr = (w >> 1) * 32, wc = (w & 1) * 32;
    const int m0 = lane & 15, q4 = lane >> 4;

    f32x4 acc[2][2] = {};

    const int rA = tid >> 3;
    const int cA = tid & 7;
    const int ksP = cA >> 2;
    const int cB = (cA & 3) * 16;
    const int cE = cA * 8;

    for (int k0 = kbeg; k0 < kend; k0 += 64) {
        uint4 a0 = *(const uint4*)(A  + (size_t)(bm + rA) * K + k0 + cE);
        uint4 a1 = *(const uint4*)(A  + (size_t)(bm + rA + 32) * K + k0 + cE);
        uint4 b0 = *(const uint4*)(Bt + (size_t)(bn + rA) * K + k0 + cE);
        uint4 b1 = *(const uint4*)(Bt + (size_t)(bn + rA + 32) * K + k0 + cE);
        __syncthreads();
        *(uint4*)(As + ksP * (64 * RSTR) + rA * RSTR + cB) = a0;
        *(uint4*)(As + ksP * (64 * RSTR) + (rA + 32) * RSTR + cB) = a1;
        *(uint4*)(Bs + ksP * (64 * RSTR) + rA * RSTR + cB) = b0;
        *(uint4*)(Bs + ksP * (64 * RSTR) + (rA + 32) * RSTR + cB) = b1;
        __syncthreads();
        short8 af[2][2], bfr[2][2];
        #pragma unroll
        for (int ks = 0; ks < 2; ++ks)
            #pragma unroll
            for (int t = 0; t < 2; ++t) {
                af[ks][t]  = *(const short8*)(As + ks * (64 * RSTR) + (wr + t * 16 + m0) * RSTR + q4 * 16);
                bfr[ks][t] = *(const short8*)(Bs + ks * (64 * RSTR) + (wc + t * 16 + m0) * RSTR + q4 * 16);
            }
        #pragma unroll
        for (int ks = 0; ks < 2; ++ks)
            #pragma unroll
            for (int mt = 0; mt < 2; ++mt)
                #pragma unroll
                for (int nt = 0; nt < 2; ++nt)
                    acc[mt][nt] = __builtin_amdgcn_mfma_f32_16x16x32_bf16(
                        af[ks][mt], bfr[ks][nt], acc[mt][nt], 0, 0, 0);
    }

    if (EPI <= 1) {
        float* C = (float*)Cv;
        #pragma unroll
        for (int mt = 0; mt < 2; ++mt)
            #pragma unroll
            for (int i = 0; i < 4; ++i) {
                int row = bm + wr + mt * 16 + q4 * 4 + i;
                #pragma unroll
                for (int nt = 0; nt < 2; ++nt) {
                    int col = bn + wc + nt * 16 + m0;
                    float v = acc[mt][nt][i];
                    if (EPI == 1) v += R[(size_t)row * N + col];
                    C[(size_t)row * N + col] = v;
                }
            }
    } else {
        bf16* C = (bf16*)Cv;
        #pragma unroll
        for (int mt = 0; mt < 2; ++mt)
            #pragma unroll
            for (int i = 0; i < 4; ++i) {
                int row = bm + wr + mt * 16 + q4 * 4 + i;
                #pragma unroll
                for (int nt = 0; nt < 2; ++nt) {
                    int col = bn + wc + nt * 16 + m0;
                    float v = acc[mt][nt][i];
                    if (EPI == 2) v = fmaxf(v, 0.0f);
                    C[(size_t)row * N + col] = __float2bfloat16(v);
                }
            }
    }
}

// ------------------------------------------------------------ GEMM kernels
// l=1,2: blocks [0,1024) ew 128-tile with XCD-aware decode (r=blk&255 keeps the
// 4 col-tiles of a row on one XCD -> bond L2 reuse); [1024,1216) fused qkv.
__launch_bounds__(256)
__global__ void qkv_ew_kernel(const bf16* __restrict__ bond, const bf16* __restrict__ ewt_l,
                              bf16* __restrict__ ew,
                              const bf16* __restrict__ xn_bf, const bf16* __restrict__ qkvt_l,
                              float* __restrict__ qkv) {
    __shared__ __align__(16) char lds[4 * 64 * RSTR];
    int blk = blockIdx.x;
    if (blk < 1024) {
        gemm128_body<3>(lds, bond, ewt_l, ew, nullptr, 32768, 512, 512,
                        blk & 255, blk >> 8);
    } else {
        int t = blk - 1024;
        int z = t >> 6;
        int rem = t & 63;
        gemm64_body<0>(lds, xn_bf, qkvt_l + (size_t)z * 262144,
                       qkv + (size_t)z * 512 * 512, nullptr,
                       512, 512, 512, rem >> 3, rem & 7, 0, 512);
    }
}

// l=0: blocks [0,8192) ew0 gather; [8192,8384) fused qkv
__launch_bounds__(256)
__global__ void ew0qkv_kernel(const int* __restrict__ adj, const bf16* __restrict__ E0,
                              bf16* __restrict__ ew,
                              const bf16* __restrict__ xn_bf, const bf16* __restrict__ qkvt0,
                              float* __restrict__ qkv) {
    __shared__ __align__(16) char lds[4 * 64 * RSTR];
    int blk = blockIdx.x;
    if (blk < 8192) {
        int gid = blk * 256 + threadIdx.x;
        int pair = gid >> 6;
        int c    = gid & 63;
        uint4 v = *(const uint4*)(E0 + (size_t)adj[pair] * H_ + c * 8);
        *(uint4*)(ew + (size_t)pair * H_ + c * 8) = v;
    } else {
        int t = blk - 8192;
        int z = t >> 6;
        int rem = t & 63;
        gemm64_body<0>(lds, xn_bf, qkvt0 + (size_t)z * 262144,
                       qkv + (size_t)z * 512 * 512, nullptr,
                       512, 512, 512, rem >> 3, rem & 7, 0, 512);
    }
}

template <int EPI, bool SPLIT>
__launch_bounds__(256)
__global__ void mfma_gemm_s(const bf16* __restrict__ A, const bf16* __restrict__ Bt,
                            void* __restrict__ Cv, const float* __restrict__ R,
                            int M, int N, int K) {
    __shared__ __align__(16) char lds[4 * 64 * RSTR];
    int kbeg = 0, kend = K;
    const bf16* B2 = Bt;
    void* C2 = Cv;
    if (SPLIT) {
        int ks = K / gridDim.z;
        kbeg = blockIdx.z * ks;
        kend = kbeg + ks;
        C2 = (void*)((float*)Cv + (size_t)blockIdx.z * M * N);
        gemm64_body<0>(lds, A, B2, C2, nullptr, M, N, K, blockIdx.x, blockIdx.y, kbeg, kend);
    } else {
        B2 = Bt + (size_t)blockIdx.z * N * K;
        if (EPI <= 1) C2 = (void*)((float*)Cv + (size_t)blockIdx.z * M * N);
        gemm64_body<EPI>(lds, A, B2, C2, R, M, N, K, blockIdx.x, blockIdx.y, kbeg, kend);
    }
}

// ---------------------------------------------------------------- embeddings
__global__ void embed_ln_kernel(const int* __restrict__ ids,
                                const float* __restrict__ emb,
                                float* __restrict__ xn, bf16* __restrict__ xn_bf) {
    int row = blockIdx.x;
    int tid = threadIdx.x;
    const float* r = emb + (size_t)ids[row] * H_;
    float x0 = r[tid], x1 = r[tid + 256];
    float s = x0 + x1, sq = x0 * x0 + x1 * x1;
    #pragma unroll
    for (int off = 32; off; off >>= 1) {
        s  += __shfl_xor(s,  off);
        sq += __shfl_xor(sq, off);
    }
    __shared__ float ls[4], lq[4];
    int w = tid >> 6;
    if ((tid & 63) == 0) { ls[w] = s; lq[w] = sq; }
    __syncthreads();
    float S = ls[0] + ls[1] + ls[2] + ls[3];
    float Q = lq[0] + lq[1] + lq[2] + lq[3];
    float mean = S * (1.0f / H_);
    float var  = Q * (1.0f / H_) - mean * mean;
    float inv  = rsqrtf(var + 1e-5f);
    float y0 = (x0 - mean) * inv, y1 = (x1 - mean) * inv;
    xn[(size_t)row * H_ + tid]       = y0;
    xn[(size_t)row * H_ + tid + 256] = y1;
    xn_bf[(size_t)row * H_ + tid]       = f2bf(y0);
    xn_bf[(size_t)row * H_ + tid + 256] = f2bf(y1);
}

__global__ void ew0_precompute(const float* __restrict__ bond_emb,
                               const bf16* __restrict__ ewt0, bf16* __restrict__ E0) {
    int t = blockIdx.x, cb = blockIdx.y, lane = threadIdx.x;
    int c = cb * 64 + lane;
    __shared__ float be[512];
    for (int h = lane; h < 512; h += 64) be[h] = bond_emb[t * 512 + h];
    __syncthreads();
    const bf16* wr = ewt0 + (size_t)c * 512;
    float acc = 0.f;
    for (int h8 = 0; h8 < 64; ++h8) {
        uint4 u = *(const uint4*)(wr + h8 * 8);
        float wf[8];
        unpack8(u, wf);
        const float* b = &be[h8 * 8];
        acc += b[0]*wf[0] + b[1]*wf[1] + b[2]*wf[2] + b[3]*wf[3]
             + b[4]*wf[4] + b[5]*wf[5] + b[6]*wf[6] + b[7]*wf[7];
    }
    E0[t * 512 + c] = f2bf(acc);
}

// ------------------------------------------------- weight transpose + cast
__global__ void transpose_sq(const float* __restrict__ Wq, const float* __restrict__ Wk,
                             const float* __restrict__ Wv, const float* __restrict__ Wew,
                             const float* __restrict__ Wst,
                             bf16* __restrict__ qkvt, bf16* __restrict__ ewt,
                             bf16* __restrict__ stackt) {
    const size_t KN = (size_t)H_ * H_;
    int z = blockIdx.z;
    const float* W; bf16* Wt;
    if (z < 12) {
        int s = z >> 2, l = z & 3;
        W  = (s == 0 ? Wq : s == 1 ? Wk : Wv) + (size_t)l * KN;
        Wt = qkvt + (size_t)l * 3 * KN + (size_t)s * KN;
    } else if (z < 16) {
        int l = z - 12;
        W = Wew + (size_t)l * KN; Wt = ewt + (size_t)l * KN;
    } else {
        int l = z - 16;
        W = Wst + (size_t)l * KN; Wt = stackt + (size_t)l * KN;
    }
    __shared__ float t[32][33];
    int k0 = blockIdx.x * 32, n0 = blockIdx.y * 32;
    int tx = threadIdx.x, ty = threadIdx.y;
    #pragma unroll
    for (int r = ty; r < 32; r += 8)
        t[r][tx] = W[(size_t)(k0 + r) * H_ + n0 + tx];
    __syncthreads();
    #pragma unroll
    for (int r = ty; r < 32; r += 8)
        Wt[(size_t)(n0 + r) * H_ + k0 + tx] = f2bf(t[tx][r]);
}

__global__ void transpose_rect(const float* __restrict__ Wf1, const float* __restrict__ Wf2,
                               bf16* __restrict__ f1t, bf16* __restrict__ f2t) {
    const size_t KN4 = (size_t)4 * H_ * H_;
    int z = blockIdx.z;
    const float* W; bf16* Wt; int K, N;
    if (z < 4) {
        if (blockIdx.x >= 16) return;
        W = Wf1 + (size_t)z * KN4; Wt = f1t + (size_t)z * KN4; K = 512; N = 2048;
    } else {
        if (blockIdx.y >= 16) return;
        W = Wf2 + (size_t)(z - 4) * KN4; Wt = f2t + (size_t)(z - 4) * KN4; K = 2048; N = 512;
    }
    __shared__ float t[32][33];
    int k0 = blockIdx.x * 32, n0 = blockIdx.y * 32;
    int tx = threadIdx.x, ty = threadIdx.y;
    #pragma unroll
    for (int r = ty; r < 32; r += 8)
        t[r][tx] = W[(size_t)(k0 + r) * N + n0 + tx];
    __syncthreads();
    #pragma unroll
    for (int r = ty; r < 32; r += 8)
        Wt[(size_t)(n0 + r) * K + k0 + tx] = f2bf(t[tx][r]);
}

// ---------------------- split-K reduce + residual + LN variants
__global__ void reduce_stack_ln(const float* __restrict__ part, const float* __restrict__ base,
                                float* __restrict__ resid, bf16* __restrict__ ffin_bf) {
    const int MN = 512 * H_;
    int row = blockIdx.x;
    int tid = threadIdx.x;
    size_t b0 = (size_t)row * H_;
    float v0 = base[b0 + tid], v1 = base[b0 + tid + 256];
    #pragma unroll
    for (int s = 0; s < 4; ++s) {
        v0 += part[(size_t)s * MN + b0 + tid];
        v1 += part[(size_t)s * MN + b0 + tid + 256];
    }
    resid[b0 + tid] = v0;
    resid[b0 + tid + 256] = v1;
    float s = v0 + v1, sq = v0 * v0 + v1 * v1;
    #pragma unroll
    for (int off = 32; off; off >>= 1) {
        s  += __shfl_xor(s,  off);
        sq += __shfl_xor(sq, off);
    }
    __shared__ float ls[4], lq[4];
    int w = tid >> 6;
    if ((tid & 63) == 0) { ls[w] = s; lq[w] = sq; }
    __syncthreads();
    float S = ls[0] + ls[1] + ls[2] + ls[3];
    float Q = lq[0] + lq[1] + lq[2] + lq[3];
    float mean = S * (1.0f / H_);
    float var  = Q * (1.0f / H_) - mean * mean;
    float inv  = rsqrtf(var + 1e-5f);
    ffin_bf[b0 + tid]       = f2bf((v0 - mean) * inv);
    ffin_bf[b0 + tid + 256] = f2bf((v1 - mean) * inv);
}

template <bool DO_LN>
__global__ void reduce_ln_kernel(const float* __restrict__ part, const float* __restrict__ resid,
                                 float* __restrict__ x, float* __restrict__ xn,
                                 bf16* __restrict__ xn_bf) {
    const int MN = 512 * H_;
    int row = blockIdx.x;
    int tid = threadIdx.x;
    size_t base = (size_t)row * H_;
    float v0 = resid[base + tid], v1 = resid[base + tid + 256];
    #pragma unroll
    for (int s = 0; s < 4; ++s) {
        v0 += part[(size_t)s * MN + base + tid];
        v1 += part[(size_t)s * MN + base + tid + 256];
    }
    x[base + tid] = v0;
    x[base + tid + 256] = v1;
    if (DO_LN) {
        float s = v0 + v1, sq = v0 * v0 + v1 * v1;
        #pragma unroll
        for (int off = 32; off; off >>= 1) {
            s  += __shfl_xor(s,  off);
            sq += __shfl_xor(sq, off);
        }
        __shared__ float ls[4], lq[4];
        int w = tid >> 6;
        if ((tid & 63) == 0) { ls[w] = s; lq[w] = sq; }
        __syncthreads();
        float S = ls[0] + ls[1] + ls[2] + ls[3];
        float Q = lq[0] + lq[1] + lq[2] + lq[3];
        float mean = S * (1.0f / H_);
        float var  = Q * (1.0f / H_) - mean * mean;
        float inv  = rsqrtf(var + 1e-5f);
        float y0 = (v0 - mean) * inv, y1 = (v1 - mean) * inv;
        xn[base + tid]       = y0;
        xn[base + tid + 256] = y1;
        xn_bf[base + tid]       = f2bf(y0);
        xn_bf[base + tid + 256] = f2bf(y1);
    }
}

// ------------------------------------------------ layer-3 implicit-ew path
// u[bi,h,k] = sum_c q[bi, h*64+c] * ewt3[h*64+c, k]   (u = q-weighted ewt rows)
// grid (8 h, 8 kb, 4 bg), 256 thr
__global__ void u_kernel(const float* __restrict__ q, const bf16* __restrict__ ewt3,
                         float* __restrict__ u) {
    int h = blockIdx.x, kb = blockIdx.y, bg = blockIdx.z;
    int tid = threadIdx.x;
    int w = tid >> 6, lane = tid & 63;
    __shared__ bf16 et[64][72];     // [c][k], padded
    __shared__ float qS[128][64];   // 32 KB
    for (int f = tid; f < 512; f += 256) {
        int c = f >> 3, ch = f & 7;
        *(uint4*)&et[c][ch * 8] =
            *(const uint4*)(ewt3 + (size_t)(h * 64 + c) * 512 + kb * 64 + ch * 8);
    }
    #pragma unroll
    for (int t = 0; t < 8; ++t) {
        int f = tid + 256 * t;      // < 2048
        int row = f >> 4, ch = f & 15;
        *(uint4*)&qS[row][ch * 4] =
            *(const uint4*)(q + (size_t)(bg * 128 + row) * 512 + h * 64 + ch * 4);
    }
    __syncthreads();
    float e[64];
    #pragma unroll
    for (int c = 0; c < 64; ++c) e[c] = __bfloat162float(et[c][lane]);
    for (int r = 0; r < 32; ++r) {
        int row = w * 32 + r;
        float acc = 0.f;
        #pragma unroll
        for (int c4 = 0; c4 < 16; ++c4) {
            float4 qv = *(const float4*)&qS[row][c4 * 4];
            acc += qv.x * e[c4 * 4] + qv.y * e[c4 * 4 + 1]
                 + qv.z * e[c4 * 4 + 2] + qv.w * e[c4 * 4 + 3];
        }
        u[((size_t)(bg * 128 + row) * 8 + h) * 512 + kb * 64 + lane] = acc;
    }
}

// s2[b,h,i,j] = bond[b,i,j,:] . u[b,i,h,:]   -- grid 512 (bi), block (64,4)
__global__ void s2_kernel(const bf16* __restrict__ bond, const float* __restrict__ u,
                          float* __restrict__ s2) {
    int bi = blockIdx.x;
    int b = bi >> 6, i = bi & 63;
    int lane = threadIdx.x, ty = threadIdx.y;
    int tid = ty * 64 + lane;
    __shared__ float uS[8][512];        // 16 KB
    __shared__ float red[4][64][9];     // padded, 9 KB
    #pragma unroll
    for (int t = 0; t < 4; ++t) {
        int f = tid + 256 * t;          // < 1024 uint4
        ((uint4*)uS)[f] = ((const uint4*)(u + (size_t)bi * 4096))[f];
    }
    __syncthreads();
    const bf16* brow = bond + ((size_t)bi * 64 + lane) * 512 + ty * 128;
    float acc[8] = {};
    #pragma unroll
    for (int c16 = 0; c16 < 16; ++c16) {
        uint4 bu = ((const uint4*)brow)[c16];
        float bfv[8];
        unpack8(bu, bfv);
        int k0 = ty * 128 + c16 * 8;
        #pragma unroll
        for (int h = 0; h < 8; ++h) {
            float4 ua = *(const float4*)&uS[h][k0];
            float4 ub = *(const float4*)&uS[h][k0 + 4];
            acc[h] += bfv[0] * ua.x + bfv[1] * ua.y + bfv[2] * ua.z + bfv[3] * ua.w
                    + bfv[4] * ub.x + bfv[5] * ub.y + bfv[6] * ub.z + bfv[7] * ub.w;
        }
    }
    #pragma unroll
    for (int h = 0; h < 8; ++h) red[ty][lane][h] = acc[h];
    __syncthreads();
    if (ty == 0) {
        #pragma unroll
        for (int h = 0; h < 8; ++h) {
            float s = red[0][lane][h] + red[1][lane][h] + red[2][lane][h] + red[3][lane][h];
            s2[(((size_t)b * 8 + h) * 64 + i) * 64 + lane] = s;
        }
    }
}

// ---------------------------------------------------------------- attention
__global__ void attn_kernel(const float* __restrict__ qkv, const bf16* __restrict__ ew,
                            const int* __restrict__ adj, bf16* __restrict__ o) {
    const float* q = qkv;
    const float* k = qkv + (size_t)512 * H_;
    const float* v = qkv + (size_t)1024 * H_;
    int bi = blockIdx.x;
    int b  = bi >> 6;
    int ty = threadIdx.y;
    int h  = blockIdx.y * 4 + ty;
    int lane = threadIdx.x;
    __shared__ float qs[4][64], as[4][64];
    qs[ty][lane] = q[(size_t)bi * H_ + h * 64 + lane];
    __syncthreads();

    int j = lane;
    const float4* k4 = (const float4*)(k + (size_t)(b * 64 + j) * H_ + h * 64);
    const uint4*  w4 = (const uint4*)(ew + ((size_t)bi * 64 + j) * H_ + h * 64);
    float acc = 0.f;
    #pragma unroll
    for (int t = 0; t < 8; ++t) {
        uint4 wu = w4[t];
        float4 ka = k4[2 * t], kb = k4[2 * t + 1];
        float wf[8];
        unpack8(wu, wf);
        const float* qq = &qs[ty][t * 8];
        acc += qq[0] * (ka.x + wf[0]) + qq[1] * (ka.y + wf[1])
             + qq[2] * (ka.z + wf[2]) + qq[3] * (ka.w + wf[3])
             + qq[4] * (kb.x + wf[4]) + qq[5] * (kb.y + wf[5])
             + qq[6] * (kb.z + wf[6]) + qq[7] * (kb.w + wf[7]);
    }
    float logit = acc * INV_SCALE;
    if (adj[(size_t)bi * 64 + j] <= 0) logit = -INFINITY;

    float m = logit;
    #pragma unroll
    for (int off = 32; off; off >>= 1) m = fmaxf(m, __shfl_xor(m, off));
    float p = expf(logit - m);
    float s = p;
    #pragma unroll
    for (int off = 32; off; off >>= 1) s += __shfl_xor(s, off);
    as[ty][lane] = p / s;
    __syncthreads();

    const float* vbase = v + (size_t)(b * 64) * H_ + h * 64;
    float oacc = 0.f;
    int d = lane;
    #pragma unroll 8
    for (int jj = 0; jj < 64; ++jj)
        oacc += as[ty][jj] * vbase[(size_t)jj * H_ + d];
    o[(size_t)bi * H_ + h * 64 + d] = __float2bfloat16(oacc);
}

// layer-3 variant: w-term from precomputed s2 (no ew)
__global__ void attn3_kernel(const float* __restrict__ qkv, const float* __restrict__ s2,
                             const int* __restrict__ adj, bf16* __restrict__ o) {
    const float* q = qkv;
    const float* k = qkv + (size_t)512 * H_;
    const float* v = qkv + (size_t)1024 * H_;
    int bi = blockIdx.x;
    int b  = bi >> 6, i = bi & 63;
    int ty = threadIdx.y;
    int h  = blockIdx.y * 4 + ty;
    int lane = threadIdx.x;
    __shared__ float qs[4][64], as[4][64];
    qs[ty][lane] = q[(size_t)bi * H_ + h * 64 + lane];
    __syncthreads();

    int j = lane;
    const float4* k4 = (const float4*)(k + (size_t)(b * 64 + j) * H_ + h * 64);
    float acc = s2[(((size_t)b * 8 + h) * 64 + i) * 64 + j];
    #pragma unroll
    for (int t = 0; t < 8; ++t) {
        float4 ka = k4[2 * t], kb = k4[2 * t + 1];
        const float* qq = &qs[ty][t * 8];
        acc += qq[0] * ka.x + qq[1] * ka.y + qq[2] * ka.z + qq[3] * ka.w
             + qq[4] * kb.x + qq[5] * kb.y + qq[6] * kb.z + qq[7] * kb.w;
    }
    float logit = acc * INV_SCALE;
    if (adj[(size_t)bi * 64 + j] <= 0) logit = -INFINITY;

    float m = logit;
    #pragma unroll
    for (int off = 32; off; off >>= 1) m = fmaxf(m, __shfl_xor(m, off));
    float p = expf(logit - m);
    float s = p;
    #pragma unroll
    for (int off = 32; off; off >>= 1) s += __shfl_xor(s, off);
    as[ty][lane] = p / s;
    __syncthreads();

    const float* vbase = v + (size_t)(b * 64) * H_ + h * 64;
    float oacc = 0.f;
    int d = lane;
    #pragma unroll 8
    for (int jj = 0; jj < 64; ++jj)
        oacc += as[ty][jj] * vbase[(size_t)jj * H_ + d];
    o[(size_t)bi * H_ + h * 64 + d] = __float2bfloat16(oacc);
}

// ---------------------------------------------------------------- edge update
__global__ void edge_kernel(const bf16* __restrict__ ew, const float* __restrict__ x,
                            bf16* __restrict__ bond) {
    int pair = blockIdx.x * 4 + threadIdx.y;
    int b = pair >> 12;
    int i = (pair >> 6) & 63;
    int j = pair & 63;
    int lane = threadIdx.x;
    const uint4*  e4  = (const uint4*)(ew + (size_t)pair * H_);
    const float4* xi4 = (const float4*)(x + (size_t)(b * 64 + i) * H_);
    const float4* xj4 = (const float4*)(x + (size_t)(b * 64 + j) * H_);
    uint4  eu = e4[lane];
    float4 a0 = xi4[lane * 2], a1 = xi4[lane * 2 + 1];
    float4 c0 = xj4[lane * 2], c1 = xj4[lane * 2 + 1];
    float ef[8], af[8], cf[8];
    unpack8(eu, ef);
    af[0] = a0.x; af[1] = a0.y; af[2] = a0.z; af[3] = a0.w;
    af[4] = a1.x; af[5] = a1.y; af[6] = a1.z; af[7] = a1.w;
    cf[0] = c0.x; cf[1] = c0.y; cf[2] = c0.z; cf[3] = c0.w;
    cf[4] = c1.x; cf[5] = c1.y; cf[6] = c1.z; cf[7] = c1.w;
    float s0 = 0.f, s1 = 0.f, s2 = 0.f;
    #pragma unroll
    for (int t = 0; t < 8; ++t) {
        s0 += ef[t] * ef[t]; s1 += ef[t] * af[t]; s2 += ef[t] * cf[t];
    }
    #pragma unroll
    for (int off = 32; off; off >>= 1) {
        s0 += __shfl_xor(s0, off);
        s1 += __shfl_xor(s1, off);
        s2 += __shfl_xor(s2, off);
    }
    float t0 = s0 * INV_SCALE, t1 = s1 * INV_SCALE, t2 = s2 * INV_SCALE;
    float m = fmaxf(t0, fmaxf(t1, t2));
    float e0 = expf(t0 - m), e1 = expf(t1 - m), e2 = expf(t2 - m);
    float inv = 1.0f / (e0 + e1 + e2);
    float w0 = e0 * inv, w1 = e1 * inv, w2 = e2 * inv;
    __align__(16) bf16 ob[8];
    #pragma unroll
    for (int t = 0; t < 8; ++t)
        ob[t] = __float2bfloat16(w0 * ef[t] + w1 * af[t] + w2 * cf[t]);
    *(uint4*)(bond + (size_t)pair * H_ + lane * 8) = *(const uint4*)ob;
}

// ---------------------------------------------------------------- head
__global__ void cls_part_kernel(const float* __restrict__ x, const float* __restrict__ Wout,
                                float* __restrict__ clspart) {
    int b  = blockIdx.x;
    int cb = blockIdx.y;
    int ks = blockIdx.z;
    int tid = threadIdx.x;
    int c  = cb * 64 + (tid & 63);
    int kk = tid >> 6;
    const float* xr = x + (size_t)(b * 64) * H_;
    int h0 = ks * 128 + kk * 32;
    float acc = 0.f;
    #pragma unroll
    for (int h = 0; h < 32; ++h)
        acc += xr[h0 + h] * Wout[(size_t)(h0 + h) * H_ + c];
    __shared__ float red[4][64];
    red[kk][tid & 63] = acc;
    __syncthreads();
    if (tid < 64) {
        float v = red[0][tid] + red[1][tid] + red[2][tid] + red[3][tid];
        clspart[((size_t)ks * 8 + b) * H_ + cb * 64 + tid] = v;
    }
}

__global__ void cls_pred2_kernel(const float* __restrict__ clspart,
                                 const float* __restrict__ Wpred,
                                 const float* __restrict__ bpred,
                                 float* __restrict__ out) {
    int b = blockIdx.x;
    int tid = threadIdx.x;
    __shared__ float red0[4], red1[4];
    float a0 = 0.f, a1 = 0.f;
    #pragma unroll
    for (int t = 0; t < 2; ++t) {
        int c = tid + t * 256;
        float v = clspart[((size_t)0 * 8 + b) * H_ + c]
                + clspart[((size_t)1 * 8 + b) * H_ + c]
                + clspart[((size_t)2 * 8 + b) * H_ + c]
                + clspart[((size_t)3 * 8 + b) * H_ + c];
        float tv = tanhf(v);
        a0 += tv * Wpred[c * 2 + 0];
        a1 += tv * Wpred[c * 2 + 1];
    }
    #pragma unroll
    for (int off = 32; off; off >>= 1) {
        a0 += __shfl_xor(a0, off);
        a1 += __shfl_xor(a1, off);
    }
    int w = tid >> 6;
    if ((tid & 63) == 0) { red0[w] = a0; red1[w] = a1; }
    __syncthreads();
    if (tid == 0) {
        float s0 = red0[0] + red0[1] + red0[2] + red0[3] + bpred[0];
        float s1 = red1[0] + red1[1] + red1[2] + red1[3] + bpred[1];
        float m = fmaxf(s0, s1);
        float e0 = expf(s0 - m), e1 = expf(s1 - m);
        float inv = 1.0f / (e0 + e1);
        out[b * 2 + 0] = e0 * inv;
        out[b * 2 + 1] = e1 * inv;
    }
}

// ---------------------------------------------------------------- launch
extern "C" void kernel_launch(void* const* d_in, const int* in_sizes, int n_in,
                              void* d_out, int out_size, void* d_ws, size_t ws_size,
                              hipStream_t stream) {
    const int*   ids      = (const int*)d_in[0];
    const int*   adj      = (const int*)d_in[1];
    const float* atom_emb = (const float*)d_in[2];
    const float* bond_emb = (const float*)d_in[3];
    const float* Wq     = (const float*)d_in[4];
    const float* Wk     = (const float*)d_in[5];
    const float* Wv     = (const float*)d_in[6];
    const float* Wew    = (const float*)d_in[7];
    const float* Wstack = (const float*)d_in[8];
    const float* Wf1    = (const float*)d_in[9];
    const float* Wf2    = (const float*)d_in[10];
    const float* Wout   = (const float*)d_in[11];
    const float* Wpred  = (const float*)d_in[12];
    const float* bpred  = (const float*)d_in[13];

    char* ws = (char*)d_ws;
    size_t off = 0;
    auto alloc = [&](size_t bytes) {
        size_t o = off;
        off += (bytes + 255) & ~(size_t)255;
        return o;
    };
    const size_t ROWS  = (size_t)B_ * N_;
    const size_t PAIRS = (size_t)B_ * N_ * N_;
    const size_t KN    = (size_t)H_ * H_;

    float* x       = (float*)(ws + alloc(ROWS * H_ * 4));
    float* xn      = (float*)(ws + alloc(ROWS * H_ * 4));
    bf16*  xn_bf   = (bf16*) (ws + alloc(ROWS * H_ * 2));
    float* qkv     = (float*)(ws + alloc(3 * ROWS * H_ * 4));
    bf16*  o_bf    = (bf16*) (ws + alloc(ROWS * H_ * 2));
    float* resid   = (float*)(ws + alloc(ROWS * H_ * 4));
    bf16*  ffin_bf = (bf16*) (ws + alloc(ROWS * H_ * 2));
    bf16*  ffh_bf  = (bf16*) (ws + alloc(ROWS * 4 * H_ * 2));
    float* part    = (float*)(ws + alloc(4 * ROWS * H_ * 4));
    float* clspart = (float*)(ws + alloc(4 * 8 * H_ * 4));
    float* ubuf    = (float*)(ws + alloc(ROWS * 8 * 512 * 4));    // 8 MB (l=3 u)
    float* s2buf   = (float*)(ws + alloc((size_t)B_ * 8 * 64 * 64 * 4)); // 8 MB
    bf16*  E0      = (bf16*) (ws + alloc(8 * H_ * 2));
    bf16*  bond    = (bf16*) (ws + alloc(PAIRS * H_ * 2));
    bf16*  ew      = (bf16*) (ws + alloc(PAIRS * H_ * 2));
    bf16*  qkvt    = (bf16*) (ws + alloc((size_t)L_ * 3 * KN * 2));
    bf16*  ewt     = (bf16*) (ws + alloc((size_t)L_ * KN * 2));
    bf16*  stackt  = (bf16*) (ws + alloc((size_t)L_ * KN * 2));
    bf16*  f1t     = (bf16*) (ws + alloc((size_t)L_ * 4 * KN * 2));
    bf16*  f2t     = (bf16*) (ws + alloc((size_t)L_ * 4 * KN * 2));
    (void)ws_size;

    embed_ln_kernel<<<512, 256, 0, stream>>>(ids, atom_emb, xn, xn_bf);

    dim3 tb(32, 8);
    transpose_sq<<<dim3(16, 16, 20), tb, 0, stream>>>(Wq, Wk, Wv, Wew, Wstack,
                                                      qkvt, ewt, stackt);
    transpose_rect<<<dim3(64, 64, 8), tb, 0, stream>>>(Wf1, Wf2, f1t, f2t);

    ew0_precompute<<<dim3(8, 8), 64, 0, stream>>>(bond_emb, ewt, E0);

    for (int l = 0; l < L_; ++l) {
        if (l == 0) {
            // ew0 gather (8192 blocks) + fused qkv (192 blocks)
            ew0qkv_kernel<<<8384, 256, 0, stream>>>(adj, E0, ew, xn_bf, qkvt, qkv);
            attn_kernel<<<dim3(512, 2), dim3(64, 4), 0, stream>>>(qkv, ew, adj, o_bf);
        } else if (l < 3) {
            qkv_ew_kernel<<<1216, 256, 0, stream>>>(
                bond, ewt + (size_t)l * KN, ew,
                xn_bf, qkvt + (size_t)l * 3 * KN, qkv);
            attn_kernel<<<dim3(512, 2), dim3(64, 4), 0, stream>>>(qkv, ew, adj, o_bf);
        } else {
            // l=3: ew never materialized -- implicit via u/s2
            mfma_gemm_s<0, false><<<dim3(8, 8, 3), 256, 0, stream>>>(
                xn_bf, qkvt + (size_t)l * 3 * KN, qkv, nullptr, 512, 512, 512);
            u_kernel<<<dim3(8, 8, 4), 256, 0, stream>>>(qkv, ewt + (size_t)l * KN, ubuf);
            s2_kernel<<<512, dim3(64, 4), 0, stream>>>(bond, ubuf, s2buf);
            attn3_kernel<<<dim3(512, 2), dim3(64, 4), 0, stream>>>(qkv, s2buf, adj, o_bf);
        }
        mfma_gemm_s<0, true><<<dim3(8, 8, 4), 256, 0, stream>>>(
            o_bf, stackt + (size_t)l * KN, part, nullptr, 512, 512, 512);
        reduce_stack_ln<<<512, 256, 0, stream>>>(part, xn, resid, ffin_bf);
        mfma_gemm_s<2, false><<<dim3(8, 32), 256, 0, stream>>>(
            ffin_bf, f1t + (size_t)l * 4 * KN, ffh_bf, nullptr, 512, 2048, 512);
        mfma_gemm_s<0, true><<<dim3(8, 8, 4), 256, 0, stream>>>(
            ffh_bf, f2t + (size_t)l * 4 * KN, part, nullptr, 512, 512, 2048);
        if (l < L_ - 1)
            reduce_ln_kernel<true><<<512, 256, 0, stream>>>(part, resid, x, xn, xn_bf);
        else
            reduce_ln_kernel<false><<<512, 256, 0, stream>>>(part, resid, x, xn, xn_bf);
        if (l < L_ - 1)
            edge_kernel<<<8192, dim3(64, 4), 0, stream>>>(ew, x, bond);
    }

    cls_part_kernel<<<dim3(8, 8, 4), 256, 0, stream>>>(x, Wout, clspart);
    cls_pred2_kernel<<<8, 256, 0, stream>>>(clspart, Wpred, bpred, (float*)d_out);
}

// Round 12
// 497.690 us; speedup vs baseline: 1.1050x; 1.1050x over previous
//
#include <hip/hip_runtime.h>
#include <hip/hip_bf16.h>

typedef __hip_bfloat16 bf16;

#define B_     8
#define N_     64
#define H_     512
#define HEADS_ 8
#define SP_    64
#define L_     4
static constexpr float INV_SCALE = 0.044194173824159216f; // 1/sqrt(512)

typedef __attribute__((ext_vector_type(8))) short short8;
typedef __attribute__((ext_vector_type(4))) float f32x4;

__device__ __forceinline__ void gload_lds16(const void* g, void* l) {
    __builtin_amdgcn_global_load_lds(
        (const __attribute__((address_space(1))) unsigned int*)g,
        (__attribute__((address_space(3))) unsigned int*)l, 16, 0, 0);
}

__device__ __forceinline__ void unpack8(uint4 u, float* f) {
    f[0] = __uint_as_float(u.x << 16); f[1] = __uint_as_float(u.x & 0xffff0000u);
    f[2] = __uint_as_float(u.y << 16); f[3] = __uint_as_float(u.y & 0xffff0000u);
    f[4] = __uint_as_float(u.z << 16); f[5] = __uint_as_float(u.z & 0xffff0000u);
    f[6] = __uint_as_float(u.w << 16); f[7] = __uint_as_float(u.w & 0xffff0000u);
}

__device__ __forceinline__ bf16 f2bf(float v) { return __float2bfloat16(v); }

__device__ __forceinline__ uint4 pack8bf(float4 a, float4 b) {
    __align__(16) bf16 t[8];
    t[0] = f2bf(a.x); t[1] = f2bf(a.y); t[2] = f2bf(a.z); t[3] = f2bf(a.w);
    t[4] = f2bf(b.x); t[5] = f2bf(b.y); t[6] = f2bf(b.z); t[7] = f2bf(b.w);
    return *(const uint4*)t;
}

#define BM 128
#define BN 128
#define BK 32
#define RSTR 80

// ------------------------------------------------------------ GEMM bodies
template <int EPI>
__device__ __forceinline__ void gemm128_body(char* lds,
        const bf16* __restrict__ A, const bf16* __restrict__ Bt,
        void* __restrict__ Cv, const float* __restrict__ R,
        int M, int N, int K, int bx, int by) {
    char* As = lds;
    char* Bs = lds + BM * 64;
    const int tid = threadIdx.x;
    const int bm = bx * BM, bn = by * BN;
    const int w = tid >> 6, lane = tid & 63;
    const int wr = (w >> 1) * 64, wc = (w & 1) * 64;
    const int m0 = lane & 15, q4 = lane >> 4;

    f32x4 acc[4][4] = {};

    const int sr = lane >> 2;
    const int scE = (((lane & 3) ^ (sr & 3)) * 8);
    const int fr = m0 * 64 + ((q4 ^ (m0 & 3)) * 16);

    for (int k0 = 0; k0 < K; k0 += BK) {
        __syncthreads();
        #pragma unroll
        for (int t = 0; t < 2; ++t) {
            gload_lds16(A  + (size_t)(bm + w * 32 + t * 16 + sr) * K + k0 + scE,
                        As + (w * 2 + t) * 1024);
            gload_lds16(Bt + (size_t)(bn + w * 32 + t * 16 + sr) * K + k0 + scE,
                        Bs + (w * 2 + t) * 1024);
        }
        __syncthreads();
        short8 af[4], bfr[4];
        #pragma unroll
        for (int t = 0; t < 4; ++t) {
            af[t]  = *(const short8*)(As + (wr / 16 + t) * 1024 + fr);
            bfr[t] = *(const short8*)(Bs + (wc / 16 + t) * 1024 + fr);
        }
        #pragma unroll
        for (int mt = 0; mt < 4; ++mt)
            #pragma unroll
            for (int nt = 0; nt < 4; ++nt)
                acc[mt][nt] = __builtin_amdgcn_mfma_f32_16x16x32_bf16(
                    af[mt], bfr[nt], acc[mt][nt], 0, 0, 0);
    }

    if (EPI <= 1) {
        float* C = (float*)Cv;
        #pragma unroll
        for (int mt = 0; mt < 4; ++mt)
            #pragma unroll
            for (int i = 0; i < 4; ++i) {
                int row = bm + wr + mt * 16 + q4 * 4 + i;
                #pragma unroll
                for (int nt = 0; nt < 4; ++nt) {
                    int col = bn + wc + nt * 16 + m0;
                    float v = acc[mt][nt][i];
                    if (EPI == 1) v += R[(size_t)row * N + col];
                    C[(size_t)row * N + col] = v;
                }
            }
    } else {
        bf16* C = (bf16*)Cv;
        #pragma unroll
        for (int mt = 0; mt < 4; ++mt)
            #pragma unroll
            for (int i = 0; i < 4; ++i) {
                int row = bm + wr + mt * 16 + q4 * 4 + i;
                #pragma unroll
                for (int nt = 0; nt < 4; ++nt) {
                    int col = bn + wc + nt * 16 + m0;
                    float v = acc[mt][nt][i];
                    if (EPI == 2) v = fmaxf(v, 0.0f);
                    C[(size_t)row * N + col] = __float2bfloat16(v);
                }
            }
    }
}

template <int EPI>
__device__ __forceinline__ void gemm64_body(char* lds,
        const bf16* __restrict__ A, const bf16* __restrict__ Bt,
        void* __restrict__ Cv, const float* __restrict__ R,
        int M, int N, int K, int bx, int by, int kbeg, int kend) {
    char* As = lds;
    char* Bs = lds + 2 * 64 * RSTR;
    const int tid = threadIdx.x;
    const int bm = bx * 64, bn = by * 64;
    const int w = tid >> 6, lane = tid & 63;
    const int wr = (w >> 1) * 32, wc = (w & 1) * 32;
    const int m0 = lane & 15, q4 = lane >> 4;

    f32x4 acc[2][2] = {};

    const int rA = tid >> 3;
    const int cA = tid & 7;
    const int ksP = cA >> 2;
    const int cB = (cA & 3) * 16;
    const int cE = cA * 8;

    for (int k0 = kbeg; k0 < kend; k0 += 64) {
        uint4 a0 = *(const uint4*)(A  + (size_t)(bm + rA) * K + k0 + cE);
        uint4 a1 = *(const uint4*)(A  + (size_t)(bm + rA + 32) * K + k0 + cE);
        uint4 b0 = *(const uint4*)(Bt + (size_t)(bn + rA) * K + k0 + cE);
        uint4 b1 = *(const uint4*)(Bt + (size_t)(bn + rA + 32) * K + k0 + cE);
        __syncthreads();
        *(uint4*)(As + ksP * (64 * RSTR) + rA * RSTR + cB) = a0;
        *(uint4*)(As + ksP * (64 * RSTR) + (rA + 32) * RSTR + cB) = a1;
        *(uint4*)(Bs + ksP * (64 * RSTR) + rA * RSTR + cB) = b0;
        *(uint4*)(Bs + ksP * (64 * RSTR) + (rA + 32) * RSTR + cB) = b1;
        __syncthreads();
        short8 af[2][2], bfr[2][2];
        #pragma unroll
        for (int ks = 0; ks < 2; ++ks)
            #pragma unroll
            for (int t = 0; t < 2; ++t) {
                af[ks][t]  = *(const short8*)(As + ks * (64 * RSTR) + (wr + t * 16 + m0) * RSTR + q4 * 16);
                bfr[ks][t] = *(const short8*)(Bs + ks * (64 * RSTR) + (wc + t * 16 + m0) * RSTR + q4 * 16);
            }
        #pragma unroll
        for (int ks = 0; ks < 2; ++ks)
            #pragma unroll
            for (int mt = 0; mt < 2; ++mt)
                #pragma unroll
                for (int nt = 0; nt < 2; ++nt)
                    acc[mt][nt] = __builtin_amdgcn_mfma_f32_16x16x32_bf16(
                        af[ks][mt], bfr[ks][nt], acc[mt][nt], 0, 0, 0);
    }

    if (EPI <= 1) {
        float* C = (float*)Cv;
        #pragma unroll
        for (int mt = 0; mt < 2; ++mt)
            #pragma unroll
            for (int i = 0; i < 4; ++i) {
                int row = bm + wr + mt * 16 + q4 * 4 + i;
                #pragma unroll
                for (int nt = 0; nt < 2; ++nt) {
                    int col = bn + wc + nt * 16 + m0;
                    float v = acc[mt][nt][i];
                    if (EPI == 1) v += R[(size_t)row * N + col];
                    C[(size_t)row * N + col] = v;
                }
            }
    } else {
        bf16* C = (bf16*)Cv;
        #pragma unroll
        for (int mt = 0; mt < 2; ++mt)
            #pragma unroll
            for (int i = 0; i < 4; ++i) {
                int row = bm + wr + mt * 16 + q4 * 4 + i;
                #pragma unroll
                for (int nt = 0; nt < 2; ++nt) {
                    int col = bn + wc + nt * 16 + m0;
                    float v = acc[mt][nt][i];
                    if (EPI == 2) v = fmaxf(v, 0.0f);
                    C[(size_t)row * N + col] = __float2bfloat16(v);
                }
            }
    }
}

// ------------------------------------------------------------ GEMM kernels
__launch_bounds__(256)
__global__ void qkv_ew_kernel(const bf16* __restrict__ bond, const bf16* __restrict__ ewt_l,
                              bf16* __restrict__ ew,
                              const bf16* __restrict__ xn_bf, const bf16* __restrict__ qkvt_l,
                              float* __restrict__ qkv) {
    __shared__ __align__(16) char lds[4 * 64 * RSTR];
    int blk = blockIdx.x;
    if (blk < 1024) {
        gemm128_body<3>(lds, bond, ewt_l, ew, nullptr, 32768, 512, 512,
                        blk & 255, blk >> 8);
    } else {
        int t = blk - 1024;
        int z = t >> 6;
        int rem = t & 63;
        gemm64_body<0>(lds, xn_bf, qkvt_l + (size_t)z * 262144,
                       qkv + (size_t)z * 512 * 512, nullptr,
                       512, 512, 512, rem >> 3, rem & 7, 0, 512);
    }
}

__launch_bounds__(256)
__global__ void ew0qkv_kernel(const int* __restrict__ adj, const bf16* __restrict__ E0,
                              bf16* __restrict__ ew,
                              const bf16* __restrict__ xn_bf, const bf16* __restrict__ qkvt0,
                              float* __restrict__ qkv) {
    __shared__ __align__(16) char lds[4 * 64 * RSTR];
    int blk = blockIdx.x;
    if (blk < 8192) {
        int gid = blk * 256 + threadIdx.x;
        int pair = gid >> 6;
        int c    = gid & 63;
        uint4 v = *(const uint4*)(E0 + (size_t)adj[pair] * H_ + c * 8);
        *(uint4*)(ew + (size_t)pair * H_ + c * 8) = v;
    } else {
        int t = blk - 8192;
        int z = t >> 6;
        int rem = t & 63;
        gemm64_body<0>(lds, xn_bf, qkvt0 + (size_t)z * 262144,
                       qkv + (size_t)z * 512 * 512, nullptr,
                       512, 512, 512, rem >> 3, rem & 7, 0, 512);
    }
}

template <int EPI, bool SPLIT>
__launch_bounds__(256)
__global__ void mfma_gemm_s(const bf16* __restrict__ A, const bf16* __restrict__ Bt,
                            void* __restrict__ Cv, const float* __restrict__ R,
                            int M, int N, int K) {
    __shared__ __align__(16) char lds[4 * 64 * RSTR];
    int kbeg = 0, kend = K;
    const bf16* B2 = Bt;
    void* C2 = Cv;
    if (SPLIT) {
        int ks = K / gridDim.z;
        kbeg = blockIdx.z * ks;
        kend = kbeg + ks;
        C2 = (void*)((float*)Cv + (size_t)blockIdx.z * M * N);
        gemm64_body<0>(lds, A, B2, C2, nullptr, M, N, K, blockIdx.x, blockIdx.y, kbeg, kend);
    } else {
        B2 = Bt + (size_t)blockIdx.z * N * K;
        if (EPI <= 1) C2 = (void*)((float*)Cv + (size_t)blockIdx.z * M * N);
        gemm64_body<EPI>(lds, A, B2, C2, R, M, N, K, blockIdx.x, blockIdx.y, kbeg, kend);
    }
}

// ------------------------------------------------ layer-3 implicit-ew path
// u[bi,h,k] = sum_d q[bi,h*64+d] * Wew3[k,h*64+d]
// MFMA 64-tile GEMM, K=64 single iteration; A = q slice (fp32 -> bf16 staged),
// Bt = wc3 (straight bf16 cast of Wew3, rows = k, d contiguous).
// grid (8 h, 8 mb, 8 nb) = 512 blocks.
__launch_bounds__(256)
__global__ void u_gemm(const float* __restrict__ q, const bf16* __restrict__ wc3,
                       float* __restrict__ u) {
    __shared__ __align__(16) char lds[4 * 64 * RSTR];
    char* As = lds;
    char* Bs = lds + 2 * 64 * RSTR;
    const int h = blockIdx.x, mb = blockIdx.y, nb = blockIdx.z;
    const int tid = threadIdx.x;
    const int w = tid >> 6, lane = tid & 63;
    const int wr = (w >> 1) * 32, wc = (w & 1) * 32;
    const int m0 = lane & 15, q4 = lane >> 4;
    const int rA = tid >> 3;
    const int cA = tid & 7;
    const int ksP = cA >> 2;
    const int cB = (cA & 3) * 16;
    const int cE = cA * 8;

    const float* Aq = q + (size_t)(mb * 64) * 512 + h * 64;
    const bf16*  Bt = wc3 + (size_t)(nb * 64) * 512 + h * 64;

    float4 fa0 = *(const float4*)(Aq + (size_t)rA * 512 + cE);
    float4 fa1 = *(const float4*)(Aq + (size_t)rA * 512 + cE + 4);
    float4 fb0 = *(const float4*)(Aq + (size_t)(rA + 32) * 512 + cE);
    float4 fb1 = *(const float4*)(Aq + (size_t)(rA + 32) * 512 + cE + 4);
    uint4 b0 = *(const uint4*)(Bt + (size_t)rA * 512 + cE);
    uint4 b1 = *(const uint4*)(Bt + (size_t)(rA + 32) * 512 + cE);
    uint4 a0 = pack8bf(fa0, fa1);
    uint4 a1 = pack8bf(fb0, fb1);
    *(uint4*)(As + ksP * (64 * RSTR) + rA * RSTR + cB) = a0;
    *(uint4*)(As + ksP * (64 * RSTR) + (rA + 32) * RSTR + cB) = a1;
    *(uint4*)(Bs + ksP * (64 * RSTR) + rA * RSTR + cB) = b0;
    *(uint4*)(Bs + ksP * (64 * RSTR) + (rA + 32) * RSTR + cB) = b1;
    __syncthreads();

    f32x4 acc[2][2] = {};
    short8 af[2][2], bfr[2][2];
    #pragma unroll
    for (int ks = 0; ks < 2; ++ks)
        #pragma unroll
        for (int t = 0; t < 2; ++t) {
            af[ks][t]  = *(const short8*)(As + ks * (64 * RSTR) + (wr + t * 16 + m0) * RSTR + q4 * 16);
            bfr[ks][t] = *(const short8*)(Bs + ks * (64 * RSTR) + (wc + t * 16 + m0) * RSTR + q4 * 16);
        }
    #pragma unroll
    for (int ks = 0; ks < 2; ++ks)
        #pragma unroll
        for (int mt = 0; mt < 2; ++mt)
            #pragma unroll
            for (int nt = 0; nt < 2; ++nt)
                acc[mt][nt] = __builtin_amdgcn_mfma_f32_16x16x32_bf16(
                    af[ks][mt], bfr[ks][nt], acc[mt][nt], 0, 0, 0);

    #pragma unroll
    for (int mt = 0; mt < 2; ++mt)
        #pragma unroll
        for (int i = 0; i < 4; ++i) {
            int row = mb * 64 + wr + mt * 16 + q4 * 4 + i;
            #pragma unroll
            for (int nt = 0; nt < 2; ++nt) {
                int col = nb * 64 + wc + nt * 16 + m0;
                u[(size_t)row * 4096 + h * 512 + col] = acc[mt][nt][i];
            }
        }
}

// straight fp32 -> bf16 cast (one-time, Wew3 -> wc3)
__global__ void cast_w3(const float* __restrict__ in, bf16* __restrict__ out) {
    int gid = blockIdx.x * 256 + threadIdx.x;    // 32768 threads, 8 elems each
    const float4* p = (const float4*)(in + (size_t)gid * 8);
    float4 a = p[0], b = p[1];
    *(uint4*)(out + (size_t)gid * 8) = pack8bf(a, b);
}

// s2[b,h,i,j] = bond[b,i,j,:] . u[b,i,h,:]   -- grid 512 (bi), block (64,4)
__global__ void s2_kernel(const bf16* __restrict__ bond, const float* __restrict__ u,
                          float* __restrict__ s2) {
    int bi = blockIdx.x;
    int b = bi >> 6, i = bi & 63;
    int lane = threadIdx.x, ty = threadIdx.y;
    int tid = ty * 64 + lane;
    __shared__ float uS[8][512];
    __shared__ float red[4][64][9];
    #pragma unroll
    for (int t = 0; t < 4; ++t) {
        int f = tid + 256 * t;
        ((uint4*)uS)[f] = ((const uint4*)(u + (size_t)bi * 4096))[f];
    }
    __syncthreads();
    const bf16* brow = bond + ((size_t)bi * 64 + lane) * 512 + ty * 128;
    float acc[8] = {};
    #pragma unroll
    for (int c16 = 0; c16 < 16; ++c16) {
        uint4 bu = ((const uint4*)brow)[c16];
        float bfv[8];
        unpack8(bu, bfv);
        int k0 = ty * 128 + c16 * 8;
        #pragma unroll
        for (int h = 0; h < 8; ++h) {
            float4 ua = *(const float4*)&uS[h][k0];
            float4 ub = *(const float4*)&uS[h][k0 + 4];
            acc[h] += bfv[0] * ua.x + bfv[1] * ua.y + bfv[2] * ua.z + bfv[3] * ua.w
                    + bfv[4] * ub.x + bfv[5] * ub.y + bfv[6] * ub.z + bfv[7] * ub.w;
        }
    }
    #pragma unroll
    for (int h = 0; h < 8; ++h) red[ty][lane][h] = acc[h];
    __syncthreads();
    if (ty == 0) {
        #pragma unroll
        for (int h = 0; h < 8; ++h) {
            float s = red[0][lane][h] + red[1][lane][h] + red[2][lane][h] + red[3][lane][h];
            s2[(((size_t)b * 8 + h) * 64 + i) * 64 + lane] = s;
        }
    }
}

// ---------------------------------------------------------------- embeddings
__global__ void embed_ln_kernel(const int* __restrict__ ids,
                                const float* __restrict__ emb,
                                float* __restrict__ xn, bf16* __restrict__ xn_bf) {
    int row = blockIdx.x;
    int tid = threadIdx.x;
    const float* r = emb + (size_t)ids[row] * H_;
    float x0 = r[tid], x1 = r[tid + 256];
    float s = x0 + x1, sq = x0 * x0 + x1 * x1;
    #pragma unroll
    for (int off = 32; off; off >>= 1) {
        s  += __shfl_xor(s,  off);
        sq += __shfl_xor(sq, off);
    }
    __shared__ float ls[4], lq[4];
    int w = tid >> 6;
    if ((tid & 63) == 0) { ls[w] = s; lq[w] = sq; }
    __syncthreads();
    float S = ls[0] + ls[1] + ls[2] + ls[3];
    float Q = lq[0] + lq[1] + lq[2] + lq[3];
    float mean = S * (1.0f / H_);
    float var  = Q * (1.0f / H_) - mean * mean;
    float inv  = rsqrtf(var + 1e-5f);
    float y0 = (x0 - mean) * inv, y1 = (x1 - mean) * inv;
    xn[(size_t)row * H_ + tid]       = y0;
    xn[(size_t)row * H_ + tid + 256] = y1;
    xn_bf[(size_t)row * H_ + tid]       = f2bf(y0);
    xn_bf[(size_t)row * H_ + tid + 256] = f2bf(y1);
}

__global__ void ew0_precompute(const float* __restrict__ bond_emb,
                               const bf16* __restrict__ ewt0, bf16* __restrict__ E0) {
    int t = blockIdx.x, cb = blockIdx.y, lane = threadIdx.x;
    int c = cb * 64 + lane;
    __shared__ float be[512];
    for (int h = lane; h < 512; h += 64) be[h] = bond_emb[t * 512 + h];
    __syncthreads();
    const bf16* wr = ewt0 + (size_t)c * 512;
    float acc = 0.f;
    for (int h8 = 0; h8 < 64; ++h8) {
        uint4 u = *(const uint4*)(wr + h8 * 8);
        float wf[8];
        unpack8(u, wf);
        const float* b = &be[h8 * 8];
        acc += b[0]*wf[0] + b[1]*wf[1] + b[2]*wf[2] + b[3]*wf[3]
             + b[4]*wf[4] + b[5]*wf[5] + b[6]*wf[6] + b[7]*wf[7];
    }
    E0[t * 512 + c] = f2bf(acc);
}

// ------------------------------------------------- weight transpose + cast
__global__ void transpose_sq(const float* __restrict__ Wq, const float* __restrict__ Wk,
                             const float* __restrict__ Wv, const float* __restrict__ Wew,
                             const float* __restrict__ Wst,
                             bf16* __restrict__ qkvt, bf16* __restrict__ ewt,
                             bf16* __restrict__ stackt) {
    const size_t KN = (size_t)H_ * H_;
    int z = blockIdx.z;
    const float* W; bf16* Wt;
    if (z < 12) {
        int s = z >> 2, l = z & 3;
        W  = (s == 0 ? Wq : s == 1 ? Wk : Wv) + (size_t)l * KN;
        Wt = qkvt + (size_t)l * 3 * KN + (size_t)s * KN;
    } else if (z < 16) {
        int l = z - 12;
        W = Wew + (size_t)l * KN; Wt = ewt + (size_t)l * KN;
    } else {
        int l = z - 16;
        W = Wst + (size_t)l * KN; Wt = stackt + (size_t)l * KN;
    }
    __shared__ float t[32][33];
    int k0 = blockIdx.x * 32, n0 = blockIdx.y * 32;
    int tx = threadIdx.x, ty = threadIdx.y;
    #pragma unroll
    for (int r = ty; r < 32; r += 8)
        t[r][tx] = W[(size_t)(k0 + r) * H_ + n0 + tx];
    __syncthreads();
    #pragma unroll
    for (int r = ty; r < 32; r += 8)
        Wt[(size_t)(n0 + r) * H_ + k0 + tx] = f2bf(t[tx][r]);
}

__global__ void transpose_rect(const float* __restrict__ Wf1, const float* __restrict__ Wf2,
                               bf16* __restrict__ f1t, bf16* __restrict__ f2t) {
    const size_t KN4 = (size_t)4 * H_ * H_;
    int z = blockIdx.z;
    const float* W; bf16* Wt; int K, N;
    if (z < 4) {
        if (blockIdx.x >= 16) return;
        W = Wf1 + (size_t)z * KN4; Wt = f1t + (size_t)z * KN4; K = 512; N = 2048;
    } else {
        if (blockIdx.y >= 16) return;
        W = Wf2 + (size_t)(z - 4) * KN4; Wt = f2t + (size_t)(z - 4) * KN4; K = 2048; N = 512;
    }
    __shared__ float t[32][33];
    int k0 = blockIdx.x * 32, n0 = blockIdx.y * 32;
    int tx = threadIdx.x, ty = threadIdx.y;
    #pragma unroll
    for (int r = ty; r < 32; r += 8)
        t[r][tx] = W[(size_t)(k0 + r) * N + n0 + tx];
    __syncthreads();
    #pragma unroll
    for (int r = ty; r < 32; r += 8)
        Wt[(size_t)(n0 + r) * K + k0 + tx] = f2bf(t[tx][r]);
}

// ---------------------- split-K reduce + residual + LN variants
__global__ void reduce_stack_ln(const float* __restrict__ part, const float* __restrict__ base,
                                float* __restrict__ resid, bf16* __restrict__ ffin_bf) {
    const int MN = 512 * H_;
    int row = blockIdx.x;
    int tid = threadIdx.x;
    size_t b0 = (size_t)row * H_;
    float v0 = base[b0 + tid], v1 = base[b0 + tid + 256];
    #pragma unroll
    for (int s = 0; s < 4; ++s) {
        v0 += part[(size_t)s * MN + b0 + tid];
        v1 += part[(size_t)s * MN + b0 + tid + 256];
    }
    resid[b0 + tid] = v0;
    resid[b0 + tid + 256] = v1;
    float s = v0 + v1, sq = v0 * v0 + v1 * v1;
    #pragma unroll
    for (int off = 32; off; off >>= 1) {
        s  += __shfl_xor(s,  off);
        sq += __shfl_xor(sq, off);
    }
    __shared__ float ls[4], lq[4];
    int w = tid >> 6;
    if ((tid & 63) == 0) { ls[w] = s; lq[w] = sq; }
    __syncthreads();
    float S = ls[0] + ls[1] + ls[2] + ls[3];
    float Q = lq[0] + lq[1] + lq[2] + lq[3];
    float mean = S * (1.0f / H_);
    float var  = Q * (1.0f / H_) - mean * mean;
    float inv  = rsqrtf(var + 1e-5f);
    ffin_bf[b0 + tid]       = f2bf((v0 - mean) * inv);
    ffin_bf[b0 + tid + 256] = f2bf((v1 - mean) * inv);
}

template <bool DO_LN>
__global__ void reduce_ln_kernel(const float* __restrict__ part, const float* __restrict__ resid,
                                 float* __restrict__ x, float* __restrict__ xn,
                                 bf16* __restrict__ xn_bf) {
    const int MN = 512 * H_;
    int row = blockIdx.x;
    int tid = threadIdx.x;
    size_t base = (size_t)row * H_;
    float v0 = resid[base + tid], v1 = resid[base + tid + 256];
    #pragma unroll
    for (int s = 0; s < 4; ++s) {
        v0 += part[(size_t)s * MN + base + tid];
        v1 += part[(size_t)s * MN + base + tid + 256];
    }
    x[base + tid] = v0;
    x[base + tid + 256] = v1;
    if (DO_LN) {
        float s = v0 + v1, sq = v0 * v0 + v1 * v1;
        #pragma unroll
        for (int off = 32; off; off >>= 1) {
            s  += __shfl_xor(s,  off);
            sq += __shfl_xor(sq, off);
        }
        __shared__ float ls[4], lq[4];
        int w = tid >> 6;
        if ((tid & 63) == 0) { ls[w] = s; lq[w] = sq; }
        __syncthreads();
        float S = ls[0] + ls[1] + ls[2] + ls[3];
        float Q = lq[0] + lq[1] + lq[2] + lq[3];
        float mean = S * (1.0f / H_);
        float var  = Q * (1.0f / H_) - mean * mean;
        float inv  = rsqrtf(var + 1e-5f);
        float y0 = (v0 - mean) * inv, y1 = (v1 - mean) * inv;
        xn[base + tid]       = y0;
        xn[base + tid + 256] = y1;
        xn_bf[base + tid]       = f2bf(y0);
        xn_bf[base + tid + 256] = f2bf(y1);
    }
}

// ---------------------------------------------------------------- attention
__global__ void attn_kernel(const float* __restrict__ qkv, const bf16* __restrict__ ew,
                            const int* __restrict__ adj, bf16* __restrict__ o) {
    const float* q = qkv;
    const float* k = qkv + (size_t)512 * H_;
    const float* v = qkv + (size_t)1024 * H_;
    int bi = blockIdx.x;
    int b  = bi >> 6;
    int ty = threadIdx.y;
    int h  = blockIdx.y * 4 + ty;
    int lane = threadIdx.x;
    __shared__ float qs[4][64], as[4][64];
    qs[ty][lane] = q[(size_t)bi * H_ + h * 64 + lane];
    __syncthreads();

    int j = lane;
    const float4* k4 = (const float4*)(k + (size_t)(b * 64 + j) * H_ + h * 64);
    const uint4*  w4 = (const uint4*)(ew + ((size_t)bi * 64 + j) * H_ + h * 64);
    float acc = 0.f;
    #pragma unroll
    for (int t = 0; t < 8; ++t) {
        uint4 wu = w4[t];
        float4 ka = k4[2 * t], kb = k4[2 * t + 1];
        float wf[8];
        unpack8(wu, wf);
        const float* qq = &qs[ty][t * 8];
        acc += qq[0] * (ka.x + wf[0]) + qq[1] * (ka.y + wf[1])
             + qq[2] * (ka.z + wf[2]) + qq[3] * (ka.w + wf[3])
             + qq[4] * (kb.x + wf[4]) + qq[5] * (kb.y + wf[5])
             + qq[6] * (kb.z + wf[6]) + qq[7] * (kb.w + wf[7]);
    }
    float logit = acc * INV_SCALE;
    if (adj[(size_t)bi * 64 + j] <= 0) logit = -INFINITY;

    float m = logit;
    #pragma unroll
    for (int off = 32; off; off >>= 1) m = fmaxf(m, __shfl_xor(m, off));
    float p = expf(logit - m);
    float s = p;
    #pragma unroll
    for (int off = 32; off; off >>= 1) s += __shfl_xor(s, off);
    as[ty][lane] = p / s;
    __syncthreads();

    const float* vbase = v + (size_t)(b * 64) * H_ + h * 64;
    float oacc = 0.f;
    int d = lane;
    #pragma unroll 8
    for (int jj = 0; jj < 64; ++jj)
        oacc += as[ty][jj] * vbase[(size_t)jj * H_ + d];
    o[(size_t)bi * H_ + h * 64 + d] = __float2bfloat16(oacc);
}

// layer-3 variant: w-term from precomputed s2 (no ew)
__global__ void attn3_kernel(const float* __restrict__ qkv, const float* __restrict__ s2,
                             const int* __restrict__ adj, bf16* __restrict__ o) {
    const float* q = qkv;
    const float* k = qkv + (size_t)512 * H_;
    const float* v = qkv + (size_t)1024 * H_;
    int bi = blockIdx.x;
    int b  = bi >> 6, i = bi & 63;
    int ty = threadIdx.y;
    int h  = blockIdx.y * 4 + ty;
    int lane = threadIdx.x;
    __shared__ float qs[4][64], as[4][64];
    qs[ty][lane] = q[(size_t)bi * H_ + h * 64 + lane];
    __syncthreads();

    int j = lane;
    const float4* k4 = (const float4*)(k + (size_t)(b * 64 + j) * H_ + h * 64);
    float acc = s2[(((size_t)b * 8 + h) * 64 + i) * 64 + j];
    #pragma unroll
    for (int t = 0; t < 8; ++t) {
        float4 ka = k4[2 * t], kb = k4[2 * t + 1];
        const float* qq = &qs[ty][t * 8];
        acc += qq[0] * ka.x + qq[1] * ka.y + qq[2] * ka.z + qq[3] * ka.w
             + qq[4] * kb.x + qq[5] * kb.y + qq[6] * kb.z + qq[7] * kb.w;
    }
    float logit = acc * INV_SCALE;
    if (adj[(size_t)bi * 64 + j] <= 0) logit = -INFINITY;

    float m = logit;
    #pragma unroll
    for (int off = 32; off; off >>= 1) m = fmaxf(m, __shfl_xor(m, off));
    float p = expf(logit - m);
    float s = p;
    #pragma unroll
    for (int off = 32; off; off >>= 1) s += __shfl_xor(s, off);
    as[ty][lane] = p / s;
    __syncthreads();

    const float* vbase = v + (size_t)(b * 64) * H_ + h * 64;
    float oacc = 0.f;
    int d = lane;
    #pragma unroll 8
    for (int jj = 0; jj < 64; ++jj)
        oacc += as[ty][jj] * vbase[(size_t)jj * H_ + d];
    o[(size_t)bi * H_ + h * 64 + d] = __float2bfloat16(oacc);
}

// ---------------------------------------------------------------- edge update
__global__ void edge_kernel(const bf16* __restrict__ ew, const float* __restrict__ x,
                            bf16* __restrict__ bond) {
    int pair = blockIdx.x * 4 + threadIdx.y;
    int b = pair >> 12;
    int i = (pair >> 6) & 63;
    int j = pair & 63;
    int lane = threadIdx.x;
    const uint4*  e4  = (const uint4*)(ew + (size_t)pair * H_);
    const float4* xi4 = (const float4*)(x + (size_t)(b * 64 + i) * H_);
    const float4* xj4 = (const float4*)(x + (size_t)(b * 64 + j) * H_);
    uint4  eu = e4[lane];
    float4 a0 = xi4[lane * 2], a1 = xi4[lane * 2 + 1];
    float4 c0 = xj4[lane * 2], c1 = xj4[lane * 2 + 1];
    float ef[8], af[8], cf[8];
    unpack8(eu, ef);
    af[0] = a0.x; af[1] = a0.y; af[2] = a0.z; af[3] = a0.w;
    af[4] = a1.x; af[5] = a1.y; af[6] = a1.z; af[7] = a1.w;
    cf[0] = c0.x; cf[1] = c0.y; cf[2] = c0.z; cf[3] = c0.w;
    cf[4] = c1.x; cf[5] = c1.y; cf[6] = c1.z; cf[7] = c1.w;
    float s0 = 0.f, s1 = 0.f, s2 = 0.f;
    #pragma unroll
    for (int t = 0; t < 8; ++t) {
        s0 += ef[t] * ef[t]; s1 += ef[t] * af[t]; s2 += ef[t] * cf[t];
    }
    #pragma unroll
    for (int off = 32; off; off >>= 1) {
        s0 += __shfl_xor(s0, off);
        s1 += __shfl_xor(s1, off);
        s2 += __shfl_xor(s2, off);
    }
    float t0 = s0 * INV_SCALE, t1 = s1 * INV_SCALE, t2 = s2 * INV_SCALE;
    float m = fmaxf(t0, fmaxf(t1, t2));
    float e0 = expf(t0 - m), e1 = expf(t1 - m), e2 = expf(t2 - m);
    float inv = 1.0f / (e0 + e1 + e2);
    float w0 = e0 * inv, w1 = e1 * inv, w2 = e2 * inv;
    __align__(16) bf16 ob[8];
    #pragma unroll
    for (int t = 0; t < 8; ++t)
        ob[t] = __float2bfloat16(w0 * ef[t] + w1 * af[t] + w2 * cf[t]);
    *(uint4*)(bond + (size_t)pair * H_ + lane * 8) = *(const uint4*)ob;
}

// ---------------------------------------------------------------- head
__global__ void cls_part_kernel(const float* __restrict__ x, const float* __restrict__ Wout,
                                float* __restrict__ clspart) {
    int b  = blockIdx.x;
    int cb = blockIdx.y;
    int ks = blockIdx.z;
    int tid = threadIdx.x;
    int c  = cb * 64 + (tid & 63);
    int kk = tid >> 6;
    const float* xr = x + (size_t)(b * 64) * H_;
    int h0 = ks * 128 + kk * 32;
    float acc = 0.f;
    #pragma unroll
    for (int h = 0; h < 32; ++h)
        acc += xr[h0 + h] * Wout[(size_t)(h0 + h) * H_ + c];
    __shared__ float red[4][64];
    red[kk][tid & 63] = acc;
    __syncthreads();
    if (tid < 64) {
        float v = red[0][tid] + red[1][tid] + red[2][tid] + red[3][tid];
        clspart[((size_t)ks * 8 + b) * H_ + cb * 64 + tid] = v;
    }
}

__global__ void cls_pred2_kernel(const float* __restrict__ clspart,
                                 const float* __restrict__ Wpred,
                                 const float* __restrict__ bpred,
                                 float* __restrict__ out) {
    int b = blockIdx.x;
    int tid = threadIdx.x;
    __shared__ float red0[4], red1[4];
    float a0 = 0.f, a1 = 0.f;
    #pragma unroll
    for (int t = 0; t < 2; ++t) {
        int c = tid + t * 256;
        float v = clspart[((size_t)0 * 8 + b) * H_ + c]
                + clspart[((size_t)1 * 8 + b) * H_ + c]
                + clspart[((size_t)2 * 8 + b) * H_ + c]
                + clspart[((size_t)3 * 8 + b) * H_ + c];
        float tv = tanhf(v);
        a0 += tv * Wpred[c * 2 + 0];
        a1 += tv * Wpred[c * 2 + 1];
    }
    #pragma unroll
    for (int off = 32; off; off >>= 1) {
        a0 += __shfl_xor(a0, off);
        a1 += __shfl_xor(a1, off);
    }
    int w = tid >> 6;
    if ((tid & 63) == 0) { red0[w] = a0; red1[w] = a1; }
    __syncthreads();
    if (tid == 0) {
        float s0 = red0[0] + red0[1] + red0[2] + red0[3] + bpred[0];
        float s1 = red1[0] + red1[1] + red1[2] + red1[3] + bpred[1];
        float m = fmaxf(s0, s1);
        float e0 = expf(s0 - m), e1 = expf(s1 - m);
        float inv = 1.0f / (e0 + e1);
        out[b * 2 + 0] = e0 * inv;
        out[b * 2 + 1] = e1 * inv;
    }
}

// ---------------------------------------------------------------- launch
extern "C" void kernel_launch(void* const* d_in, const int* in_sizes, int n_in,
                              void* d_out, int out_size, void* d_ws, size_t ws_size,
                              hipStream_t stream) {
    const int*   ids      = (const int*)d_in[0];
    const int*   adj      = (const int*)d_in[1];
    const float* atom_emb = (const float*)d_in[2];
    const float* bond_emb = (const float*)d_in[3];
    const float* Wq     = (const float*)d_in[4];
    const float* Wk     = (const float*)d_in[5];
    const float* Wv     = (const float*)d_in[6];
    const float* Wew    = (const float*)d_in[7];
    const float* Wstack = (const float*)d_in[8];
    const float* Wf1    = (const float*)d_in[9];
    const float* Wf2    = (const float*)d_in[10];
    const float* Wout   = (const float*)d_in[11];
    const float* Wpred  = (const float*)d_in[12];
    const float* bpred  = (const float*)d_in[13];

    char* ws = (char*)d_ws;
    size_t off = 0;
    auto alloc = [&](size_t bytes) {
        size_t o = off;
        off += (bytes + 255) & ~(size_t)255;
        return o;
    };
    const size_t ROWS  = (size_t)B_ * N_;
    const size_t PAIRS = (size_t)B_ * N_ * N_;
    const size_t KN    = (size_t)H_ * H_;

    float* x       = (float*)(ws + alloc(ROWS * H_ * 4));
    float* xn      = (float*)(ws + alloc(ROWS * H_ * 4));
    bf16*  xn_bf   = (bf16*) (ws + alloc(ROWS * H_ * 2));
    float* qkv     = (float*)(ws + alloc(3 * ROWS * H_ * 4));
    bf16*  o_bf    = (bf16*) (ws + alloc(ROWS * H_ * 2));
    float* resid   = (float*)(ws + alloc(ROWS * H_ * 4));
    bf16*  ffin_bf = (bf16*) (ws + alloc(ROWS * H_ * 2));
    bf16*  ffh_bf  = (bf16*) (ws + alloc(ROWS * 4 * H_ * 2));
    float* part    = (float*)(ws + alloc(4 * ROWS * H_ * 4));
    float* clspart = (float*)(ws + alloc(4 * 8 * H_ * 4));
    float* ubuf    = (float*)(ws + alloc(ROWS * 8 * 512 * 4));          // 8 MB
    float* s2buf   = (float*)(ws + alloc((size_t)B_ * 8 * 64 * 64 * 4)); // 8 MB
    bf16*  wc3     = (bf16*) (ws + alloc(KN * 2));                       // 512 KB
    bf16*  E0      = (bf16*) (ws + alloc(8 * H_ * 2));
    bf16*  bond    = (bf16*) (ws + alloc(PAIRS * H_ * 2));
    bf16*  ew      = (bf16*) (ws + alloc(PAIRS * H_ * 2));
    bf16*  qkvt    = (bf16*) (ws + alloc((size_t)L_ * 3 * KN * 2));
    bf16*  ewt     = (bf16*) (ws + alloc((size_t)L_ * KN * 2));
    bf16*  stackt  = (bf16*) (ws + alloc((size_t)L_ * KN * 2));
    bf16*  f1t     = (bf16*) (ws + alloc((size_t)L_ * 4 * KN * 2));
    bf16*  f2t     = (bf16*) (ws + alloc((size_t)L_ * 4 * KN * 2));
    (void)ws_size;

    embed_ln_kernel<<<512, 256, 0, stream>>>(ids, atom_emb, xn, xn_bf);

    dim3 tb(32, 8);
    transpose_sq<<<dim3(16, 16, 20), tb, 0, stream>>>(Wq, Wk, Wv, Wew, Wstack,
                                                      qkvt, ewt, stackt);
    transpose_rect<<<dim3(64, 64, 8), tb, 0, stream>>>(Wf1, Wf2, f1t, f2t);

    ew0_precompute<<<dim3(8, 8), 64, 0, stream>>>(bond_emb, ewt, E0);
    cast_w3<<<128, 256, 0, stream>>>(Wew + 3 * KN, wc3);   // Wew3 bf16 straight cast

    for (int l = 0; l < L_; ++l) {
        if (l == 0) {
            ew0qkv_kernel<<<8384, 256, 0, stream>>>(adj, E0, ew, xn_bf, qkvt, qkv);
            attn_kernel<<<dim3(512, 2), dim3(64, 4), 0, stream>>>(qkv, ew, adj, o_bf);
        } else if (l < 3) {
            qkv_ew_kernel<<<1216, 256, 0, stream>>>(
                bond, ewt + (size_t)l * KN, ew,
                xn_bf, qkvt + (size_t)l * 3 * KN, qkv);
            attn_kernel<<<dim3(512, 2), dim3(64, 4), 0, stream>>>(qkv, ew, adj, o_bf);
        } else {
            // l=3: ew never materialized -- implicit via u/s2 (u via MFMA now)
            mfma_gemm_s<0, false><<<dim3(8, 8, 3), 256, 0, stream>>>(
                xn_bf, qkvt + (size_t)l * 3 * KN, qkv, nullptr, 512, 512, 512);
            u_gemm<<<dim3(8, 8, 8), 256, 0, stream>>>(qkv, wc3, ubuf);
            s2_kernel<<<512, dim3(64, 4), 0, stream>>>(bond, ubuf, s2buf);
            attn3_kernel<<<dim3(512, 2), dim3(64, 4), 0, stream>>>(qkv, s2buf, adj, o_bf);
        }
        mfma_gemm_s<0, true><<<dim3(8, 8, 4), 256, 0, stream>>>(
            o_bf, stackt + (size_t)l * KN, part, nullptr, 512, 512, 512);
        reduce_stack_ln<<<512, 256, 0, stream>>>(part, xn, resid, ffin_bf);
        mfma_gemm_s<2, false><<<dim3(8, 32), 256, 0, stream>>>(
            ffin_bf, f1t + (size_t)l * 4 * KN, ffh_bf, nullptr, 512, 2048, 512);
        mfma_gemm_s<0, true><<<dim3(8, 8, 4), 256, 0, stream>>>(
            ffh_bf, f2t + (size_t)l * 4 * KN, part, nullptr, 512, 512, 2048);
        if (l < L_ - 1)
            reduce_ln_kernel<true><<<512, 256, 0, stream>>>(part, resid, x, xn, xn_bf);
        else
            reduce_ln_kernel<false><<<512, 256, 0, stream>>>(part, resid, x, xn, xn_bf);
        if (l < L_ - 1)
            edge_kernel<<<8192, dim3(64, 4), 0, stream>>>(ew, x, bond);
    }

    cls_part_kernel<<<dim3(8, 8, 4), 256, 0, stream>>>(x, Wout, clspart);
    cls_pred2_kernel<<<8, 256, 0, stream>>>(clspart, Wpred, bpred, (float*)d_out);
}